// Round 10
// baseline (519.968 us; speedup 1.0000x reference)
//
#include <hip/hip_runtime.h>
#include <math.h>

typedef unsigned short u16;
typedef unsigned int u32;
typedef __bf16 bf16x8 __attribute__((ext_vector_type(8)));
typedef float f32x4 __attribute__((ext_vector_type(4)));

#define MFMA16(a, b, c) __builtin_amdgcn_mfma_f32_16x16x32_bf16(a, b, c, 0, 0, 0)

__device__ __forceinline__ float b2f(u16 u) {
    union { u32 i; float f; } w;
    w.i = ((u32)u) << 16;
    return w.f;
}

__device__ __forceinline__ u16 f2b(float f) {
    union { float f; u32 i; } w;
    w.f = f;
    u32 x = w.i;
    u32 r = (x + 0x7fffu + ((x >> 16) & 1u)) >> 16;  // RNE
    return (u16)r;
}

__device__ __forceinline__ void unpack8(uint4 u, float* v) {
    v[0] = b2f((u16)(u.x & 0xffff)); v[1] = b2f((u16)(u.x >> 16));
    v[2] = b2f((u16)(u.y & 0xffff)); v[3] = b2f((u16)(u.y >> 16));
    v[4] = b2f((u16)(u.z & 0xffff)); v[5] = b2f((u16)(u.z >> 16));
    v[6] = b2f((u16)(u.w & 0xffff)); v[7] = b2f((u16)(u.w >> 16));
}

__device__ __forceinline__ u32 pack2(float a, float b) {
    return (u32)f2b(a) | ((u32)f2b(b) << 16);
}

// ---------------------------------------------------------------------------
// Input dtype detector: flag=1 -> fp32 inputs (verified in R2; R6 version).
// ---------------------------------------------------------------------------
__global__ __launch_bounds__(256) void detect_k(const u32* __restrict__ x, int* __restrict__ flag)
{
    __shared__ int cnt[256];
    int c = 0;
#pragma unroll 4
    for (int i = 0; i < 256; ++i) {
        const u32 w = x[threadIdx.x * 256 + i];
        const u32 e = (w >> 7) & 0xFF;
        c += (e < 0x20 || e > 0x4F) ? 1 : 0;
    }
    cnt[threadIdx.x] = c;
    __syncthreads();
    if (threadIdx.x == 0) {
        int t = 0;
        for (int i = 0; i < 256; ++i) t += cnt[i];
        *flag = (t > 16384) ? 1 : 0;
    }
}

// Convert x and context in one dispatch: blockIdx.y selects tensor.
__global__ __launch_bounds__(256) void conv2_k(
    const void* __restrict__ a, const void* __restrict__ b,
    u16* __restrict__ oa, u16* __restrict__ ob, int n, const int* __restrict__ flag)
{
    const int f = *flag;
    const void* in = blockIdx.y ? b : a;
    u16* out = blockIdx.y ? ob : oa;
    const int i = (blockIdx.x * 256 + threadIdx.x) * 8;
    if (i >= n) return;
    if (f) {
        const float* p = (const float*)in + i;
        uint4 o;
        o.x = pack2(p[0], p[1]); o.y = pack2(p[2], p[3]);
        o.z = pack2(p[4], p[5]); o.w = pack2(p[6], p[7]);
        *(uint4*)(out + i) = o;
    } else {
        *(uint4*)(out + i) = *(const uint4*)((const u16*)in + i);
    }
}

struct PtrTab {
    const void* p[16];
    int off[16];
    int cnt[16];
};

__global__ __launch_bounds__(256) void conv_small_k(
    PtrTab t, u16* __restrict__ out, const int* __restrict__ flag)
{
    const int f = *flag;
    const void* src = t.p[blockIdx.x];
    const int n = t.cnt[blockIdx.x];
    u16* dst = out + t.off[blockIdx.x];
    for (int i = threadIdx.x; i < n; i += 256)
        dst[i] = f ? f2b(((const float*)src)[i]) : ((const u16*)src)[i];
}

// ---------------------------------------------------------------------------
// Generic transpose: in [rows][cols] -> out bf16 [cols][rows].
// ---------------------------------------------------------------------------
__global__ __launch_bounds__(256) void transpose_k(
    const void* __restrict__ in, u16* __restrict__ out, int rows, int cols,
    const int* __restrict__ flag)
{
    const int f = *flag;
    __shared__ u16 t[64][65];
    const int tid = threadIdx.x;
    const int lr = tid >> 4;
    const int lc = (tid & 15) * 4;
    const int r0 = blockIdx.y * 64, c0 = blockIdx.x * 64;
#pragma unroll
    for (int i = 0; i < 4; ++i) {
        const size_t off = (size_t)(r0 + i * 16 + lr) * cols + c0 + lc;
        if (f) {
            const float* p = (const float*)in + off;
            t[i * 16 + lr][lc + 0] = f2b(p[0]);
            t[i * 16 + lr][lc + 1] = f2b(p[1]);
            t[i * 16 + lr][lc + 2] = f2b(p[2]);
            t[i * 16 + lr][lc + 3] = f2b(p[3]);
        } else {
            const u16* p = (const u16*)in + off;
            t[i * 16 + lr][lc + 0] = p[0];
            t[i * 16 + lr][lc + 1] = p[1];
            t[i * 16 + lr][lc + 2] = p[2];
            t[i * 16 + lr][lc + 3] = p[3];
        }
    }
    __syncthreads();
#pragma unroll
    for (int i = 0; i < 4; ++i) {
        const int rr = i * 16 + lr;
        uint2 o;
        o.x = (u32)t[lc + 0][rr] | ((u32)t[lc + 1][rr] << 16);
        o.y = (u32)t[lc + 2][rr] | ((u32)t[lc + 3][rr] << 16);
        *(uint2*)(out + (size_t)(c0 + rr) * rows + r0 + lc) = o;
    }
}

// ---------------------------------------------------------------------------
// Fused transpose of the 6 head-blocked weights [16,1024,64] -> [1024,1024].
// grid (1, 16, 96): z = w*16 + h.
// ---------------------------------------------------------------------------
__global__ __launch_bounds__(256) void transpose6_k(
    PtrTab tab, u16* __restrict__ wT, const int* __restrict__ flag)
{
    const int f = *flag;
    __shared__ u16 t[64][65];
    const int tid = threadIdx.x;
    const int lr = tid >> 4;
    const int lc = (tid & 15) * 4;
    const int w = blockIdx.z >> 4, h = blockIdx.z & 15;
    const void* in = tab.p[w];
    u16* out = wT + (size_t)w * (1u << 20) + h * 65536;
    const size_t ibase = (size_t)h * 65536;
    const int r0 = blockIdx.y * 64;
#pragma unroll
    for (int i = 0; i < 4; ++i) {
        const size_t off = ibase + (size_t)(r0 + i * 16 + lr) * 64 + lc;
        if (f) {
            const float* p = (const float*)in + off;
            t[i * 16 + lr][lc + 0] = f2b(p[0]);
            t[i * 16 + lr][lc + 1] = f2b(p[1]);
            t[i * 16 + lr][lc + 2] = f2b(p[2]);
            t[i * 16 + lr][lc + 3] = f2b(p[3]);
        } else {
            const u16* p = (const u16*)in + off;
            t[i * 16 + lr][lc + 0] = p[0];
            t[i * 16 + lr][lc + 1] = p[1];
            t[i * 16 + lr][lc + 2] = p[2];
            t[i * 16 + lr][lc + 3] = p[3];
        }
    }
    __syncthreads();
#pragma unroll
    for (int i = 0; i < 4; ++i) {
        const int rr = i * 16 + lr;
        uint2 o;
        o.x = (u32)t[lc + 0][rr] | ((u32)t[lc + 1][rr] << 16);
        o.y = (u32)t[lc + 2][rr] | ((u32)t[lc + 3][rr] << 16);
        *(uint2*)(out + (size_t)rr * 1024 + r0 + lc) = o;
    }
}

// ---------------------------------------------------------------------------
// Grouped projection GEMM, BK=64 panelized. SA-Q/K/V (A=x) + CA-K/V (A=ctx).
// M=4096, K=1024. grid (40, 32) natural map (R9: XCD swizzle reverted — it
// cut FETCH 77->54 MB but cost +13 us). R10: register-prefetch staging
// (attn-verified): next tile loads issue after the consume barrier and
// complete during MFMA — the barrier no longer drains global traffic.
// ---------------------------------------------------------------------------
__global__ __launch_bounds__(256) void gemm_qkv_k(
    const u16* __restrict__ X, const u16* __restrict__ CTX,
    const u16* __restrict__ wT, const u16* __restrict__ bias,
    u16* __restrict__ Qo, u16* __restrict__ Ksa, u16* __restrict__ Vsa,
    u16* __restrict__ Kca, u16* __restrict__ Vca)
{
    __shared__ u16 sA[2][128 * 32];
    __shared__ u16 sB[2][128 * 32];
    const int tid = threadIdx.x;
    const int wave = tid >> 6;
    const int lane = tid & 63;
    const int bx = blockIdx.x;
    const int seg = bx >> 3, c8 = bx & 7;
    const int m0 = blockIdx.y * 128;
    const int wm = (wave >> 1) * 64;
    const int wn = (wave & 1) * 64;
    const u16* A = (seg < 3) ? X : CTX;

    const int lrow = lane >> 2;
    const int lcol = (lane & 3) * 8;
    const u16* gA = A + (size_t)(m0 + wave * 16 + lrow) * 1024 + lcol;
    const u16* gB = wT + (size_t)(bx * 128 + wave * 16 + lrow) * 1024 + lcol;
    const int lofs = wave * 16 * 32;

    // per-lane LDS slots replicating global_load_lds's base + lane*16B
    u16* dA0 = &sA[0][lofs] + lane * 8;
    u16* dA1 = &sA[1][lofs] + lane * 8;
    u16* dA2 = &sA[0][64 * 32 + lofs] + lane * 8;
    u16* dA3 = &sA[1][64 * 32 + lofs] + lane * 8;
    u16* dB0 = &sB[0][lofs] + lane * 8;
    u16* dB1 = &sB[1][lofs] + lane * 8;
    u16* dB2 = &sB[0][64 * 32 + lofs] + lane * 8;
    u16* dB3 = &sB[1][64 * 32 + lofs] + lane * 8;

    uint4 rA0 = *(const uint4*)(gA);
    uint4 rA1 = *(const uint4*)(gA + 32);
    uint4 rA2 = *(const uint4*)(gA + (size_t)64 * 1024);
    uint4 rA3 = *(const uint4*)(gA + (size_t)64 * 1024 + 32);
    uint4 rB0 = *(const uint4*)(gB);
    uint4 rB1 = *(const uint4*)(gB + 32);
    uint4 rB2 = *(const uint4*)(gB + (size_t)64 * 1024);
    uint4 rB3 = *(const uint4*)(gB + (size_t)64 * 1024 + 32);

    f32x4 acc[4][4];
#pragma unroll
    for (int i = 0; i < 4; ++i)
#pragma unroll
        for (int j = 0; j < 4; ++j) acc[i][j] = (f32x4){0.f, 0.f, 0.f, 0.f};

    const int q15 = lane & 15;
    const int koff = (lane >> 4) * 8;

    for (int k0 = 0; k0 < 1024; k0 += 64) {
        __syncthreads();
        *(uint4*)dA0 = rA0; *(uint4*)dA1 = rA1;
        *(uint4*)dA2 = rA2; *(uint4*)dA3 = rA3;
        *(uint4*)dB0 = rB0; *(uint4*)dB1 = rB1;
        *(uint4*)dB2 = rB2; *(uint4*)dB3 = rB3;
        __syncthreads();
        if (k0 < 1024 - 64) {   // prefetch next tile; completes during MFMA
            rA0 = *(const uint4*)(gA + k0 + 64);
            rA1 = *(const uint4*)(gA + k0 + 96);
            rA2 = *(const uint4*)(gA + (size_t)64 * 1024 + k0 + 64);
            rA3 = *(const uint4*)(gA + (size_t)64 * 1024 + k0 + 96);
            rB0 = *(const uint4*)(gB + k0 + 64);
            rB1 = *(const uint4*)(gB + k0 + 96);
            rB2 = *(const uint4*)(gB + (size_t)64 * 1024 + k0 + 64);
            rB3 = *(const uint4*)(gB + (size_t)64 * 1024 + k0 + 96);
        }
#pragma unroll 1
        for (int p = 0; p < 2; ++p) {
            bf16x8 af[4], bfr[4];
#pragma unroll
            for (int mt = 0; mt < 4; ++mt)
                af[mt] = *(const bf16x8*)(&sA[p][(wm + mt * 16 + q15) * 32 + koff]);
#pragma unroll
            for (int nt = 0; nt < 4; ++nt)
                bfr[nt] = *(const bf16x8*)(&sB[p][(wn + nt * 16 + q15) * 32 + koff]);
#pragma unroll
            for (int mt = 0; mt < 4; ++mt)
#pragma unroll
                for (int nt = 0; nt < 4; ++nt)
                    acc[mt][nt] = MFMA16(af[mt], bfr[nt], acc[mt][nt]);
        }
    }

    u16* outp;
    int vt;
    switch (seg) {
        case 0: outp = Qo;  vt = 0; break;
        case 1: outp = Ksa; vt = 0; break;
        case 2: outp = Vsa; vt = 1; break;
        case 3: outp = Kca; vt = 0; break;
        default: outp = Vca; vt = 1; break;
    }
    const int rq = (lane >> 4) * 4;
#pragma unroll
    for (int nt = 0; nt < 4; ++nt) {
        const int col = c8 * 128 + wn + nt * 16 + q15;
        const float bv = b2f(bias[bx * 128 + wn + nt * 16 + q15]);
#pragma unroll
        for (int mt = 0; mt < 4; ++mt) {
            const int row = m0 + wm + mt * 16 + rq;
            f32x4 v = acc[mt][nt];
            if (vt) {
                const int bb = row >> 10, tt = row & 1023;
                const int hh = col >> 6, rr = col & 63;
                const size_t idx = ((((size_t)bb * 16 + hh) * 64 + rr) << 10) + tt;
                uint2 o;
                o.x = pack2(v[0] + bv, v[1] + bv);
                o.y = pack2(v[2] + bv, v[3] + bv);
                *(uint2*)(outp + idx) = o;
            } else {
#pragma unroll
                for (int e = 0; e < 4; ++e)
                    outp[(size_t)(row + e) * 1024 + col] = f2b(v[e] + bv);
            }
        }
    }
}

// ---------------------------------------------------------------------------
// GEMM 128x128 tile, BK=64 panelized, register-prefetch staging (FFN1).
// grid (N/128, M/128).
// ---------------------------------------------------------------------------
__global__ __launch_bounds__(256) void gemm_bt(
    const u16* __restrict__ A, const u16* __restrict__ Bt,
    const u16* __restrict__ bias, const u16* __restrict__ resid,
    u16* __restrict__ C, int M, int N, int K, int flags)
{
    __shared__ u16 sA[2][128 * 32];
    __shared__ u16 sB[2][128 * 32];
    const int tid = threadIdx.x;
    const int wave = tid >> 6;
    const int lane = tid & 63;
    const int m0 = blockIdx.y * 128;
    const int n0 = blockIdx.x * 128;
    const int wm = (wave >> 1) * 64;
    const int wn = (wave & 1) * 64;

    const int lrow = lane >> 2;
    const int lcol = (lane & 3) * 8;
    const u16* gA = A + (size_t)(m0 + wave * 16 + lrow) * K + lcol;
    const u16* gB = Bt + (size_t)(n0 + wave * 16 + lrow) * K + lcol;
    const int lofs = wave * 16 * 32;

    u16* dA0 = &sA[0][lofs] + lane * 8;
    u16* dA1 = &sA[1][lofs] + lane * 8;
    u16* dA2 = &sA[0][64 * 32 + lofs] + lane * 8;
    u16* dA3 = &sA[1][64 * 32 + lofs] + lane * 8;
    u16* dB0 = &sB[0][lofs] + lane * 8;
    u16* dB1 = &sB[1][lofs] + lane * 8;
    u16* dB2 = &sB[0][64 * 32 + lofs] + lane * 8;
    u16* dB3 = &sB[1][64 * 32 + lofs] + lane * 8;

    uint4 rA0 = *(const uint4*)(gA);
    uint4 rA1 = *(const uint4*)(gA + 32);
    uint4 rA2 = *(const uint4*)(gA + (size_t)64 * K);
    uint4 rA3 = *(const uint4*)(gA + (size_t)64 * K + 32);
    uint4 rB0 = *(const uint4*)(gB);
    uint4 rB1 = *(const uint4*)(gB + 32);
    uint4 rB2 = *(const uint4*)(gB + (size_t)64 * K);
    uint4 rB3 = *(const uint4*)(gB + (size_t)64 * K + 32);

    f32x4 acc[4][4];
#pragma unroll
    for (int i = 0; i < 4; ++i)
#pragma unroll
        for (int j = 0; j < 4; ++j) acc[i][j] = (f32x4){0.f, 0.f, 0.f, 0.f};

    const int q15 = lane & 15;
    const int koff = (lane >> 4) * 8;

    for (int k0 = 0; k0 < K; k0 += 64) {
        __syncthreads();
        *(uint4*)dA0 = rA0; *(uint4*)dA1 = rA1;
        *(uint4*)dA2 = rA2; *(uint4*)dA3 = rA3;
        *(uint4*)dB0 = rB0; *(uint4*)dB1 = rB1;
        *(uint4*)dB2 = rB2; *(uint4*)dB3 = rB3;
        __syncthreads();
        if (k0 < K - 64) {
            rA0 = *(const uint4*)(gA + k0 + 64);
            rA1 = *(const uint4*)(gA + k0 + 96);
            rA2 = *(const uint4*)(gA + (size_t)64 * K + k0 + 64);
            rA3 = *(const uint4*)(gA + (size_t)64 * K + k0 + 96);
            rB0 = *(const uint4*)(gB + k0 + 64);
            rB1 = *(const uint4*)(gB + k0 + 96);
            rB2 = *(const uint4*)(gB + (size_t)64 * K + k0 + 64);
            rB3 = *(const uint4*)(gB + (size_t)64 * K + k0 + 96);
        }
#pragma unroll 1
        for (int p = 0; p < 2; ++p) {
            bf16x8 af[4], bfr[4];
#pragma unroll
            for (int mt = 0; mt < 4; ++mt)
                af[mt] = *(const bf16x8*)(&sA[p][(wm + mt * 16 + q15) * 32 + koff]);
#pragma unroll
            for (int nt = 0; nt < 4; ++nt)
                bfr[nt] = *(const bf16x8*)(&sB[p][(wn + nt * 16 + q15) * 32 + koff]);
#pragma unroll
            for (int mt = 0; mt < 4; ++mt)
#pragma unroll
                for (int nt = 0; nt < 4; ++nt)
                    acc[mt][nt] = MFMA16(af[mt], bfr[nt], acc[mt][nt]);
        }
    }

    const int rq = (lane >> 4) * 4;
#pragma unroll
    for (int nt = 0; nt < 4; ++nt) {
        const int col = n0 + wn + nt * 16 + q15;
        const float bv = b2f(bias[col]);
#pragma unroll
        for (int mt = 0; mt < 4; ++mt) {
            const int row = m0 + wm + mt * 16 + rq;
            f32x4 v = acc[mt][nt];
#pragma unroll
            for (int e = 0; e < 4; ++e) {
                float val = v[e] + bv;
                if (flags & 1) val = fmaxf(val, 0.f);
                const size_t o = (size_t)(row + e) * N + col;
                if (resid) val += b2f(resid[o]);
                C[o] = f2b(val);
            }
        }
    }
}

// ---------------------------------------------------------------------------
// GEMM 64x128 tile, BK=64 panelized, register-prefetch staging. N=1024
// shapes (K=1024). grid (M/64, 8).
// ---------------------------------------------------------------------------
__global__ __launch_bounds__(256) void gemm_n1k(
    const u16* __restrict__ A, const u16* __restrict__ Bt,
    const u16* __restrict__ bias, const u16* __restrict__ resid,
    u16* __restrict__ C, int M, int N, int K, int flags)
{
    __shared__ u16 sA[2][64 * 32];
    __shared__ u16 sB[2][128 * 32];
    const int tid = threadIdx.x;
    const int wave = tid >> 6;
    const int lane = tid & 63;
    const int m0 = blockIdx.x * 64;
    const int n0 = blockIdx.y * 128;
    const int wm = (wave >> 1) * 32;
    const int wn = (wave & 1) * 64;

    const int lrow = lane >> 2;
    const int lcol = (lane & 3) * 8;
    const u16* gA = A + (size_t)(m0 + wave * 16 + lrow) * K + lcol;
    const u16* gB = Bt + (size_t)(n0 + wave * 32 + lrow) * K + lcol;
    const u16* gB2 = gB + (size_t)16 * K;
    const int lofsA = wave * 16 * 32;
    const int lofsB = wave * 32 * 32;

    u16* dA0 = &sA[0][lofsA] + lane * 8;
    u16* dA1 = &sA[1][lofsA] + lane * 8;
    u16* dB0 = &sB[0][lofsB] + lane * 8;
    u16* dB1 = &sB[1][lofsB] + lane * 8;
    u16* dB2 = &sB[0][lofsB + 16 * 32] + lane * 8;
    u16* dB3 = &sB[1][lofsB + 16 * 32] + lane * 8;

    uint4 rA0 = *(const uint4*)(gA);
    uint4 rA1 = *(const uint4*)(gA + 32);
    uint4 rB0 = *(const uint4*)(gB);
    uint4 rB1 = *(const uint4*)(gB + 32);
    uint4 rB2 = *(const uint4*)(gB2);
    uint4 rB3 = *(const uint4*)(gB2 + 32);

    f32x4 acc[2][4];
#pragma unroll
    for (int i = 0; i < 2; ++i)
#pragma unroll
        for (int j = 0; j < 4; ++j) acc[i][j] = (f32x4){0.f, 0.f, 0.f, 0.f};

    const int q15 = lane & 15;
    const int koff = (lane >> 4) * 8;

    for (int k0 = 0; k0 < K; k0 += 64) {
        __syncthreads();
        *(uint4*)dA0 = rA0; *(uint4*)dA1 = rA1;
        *(uint4*)dB0 = rB0; *(uint4*)dB1 = rB1;
        *(uint4*)dB2 = rB2; *(uint4*)dB3 = rB3;
        __syncthreads();
        if (k0 < K - 64) {
            rA0 = *(const uint4*)(gA + k0 + 64);
            rA1 = *(const uint4*)(gA + k0 + 96);
            rB0 = *(const uint4*)(gB + k0 + 64);
            rB1 = *(const uint4*)(gB + k0 + 96);
            rB2 = *(const uint4*)(gB2 + k0 + 64);
            rB3 = *(const uint4*)(gB2 + k0 + 96);
        }
#pragma unroll 1
        for (int p = 0; p < 2; ++p) {
            bf16x8 af[2], bfr[4];
#pragma unroll
            for (int mt = 0; mt < 2; ++mt)
                af[mt] = *(const bf16x8*)(&sA[p][(wm + mt * 16 + q15) * 32 + koff]);
#pragma unroll
            for (int nt = 0; nt < 4; ++nt)
                bfr[nt] = *(const bf16x8*)(&sB[p][(wn + nt * 16 + q15) * 32 + koff]);
#pragma unroll
            for (int mt = 0; mt < 2; ++mt)
#pragma unroll
                for (int nt = 0; nt < 4; ++nt)
                    acc[mt][nt] = MFMA16(af[mt], bfr[nt], acc[mt][nt]);
        }
    }

    const int rq = (lane >> 4) * 4;
#pragma unroll
    for (int nt = 0; nt < 4; ++nt) {
        const int col = n0 + wn + nt * 16 + q15;
        const float bv = b2f(bias[col]);
#pragma unroll
        for (int mt = 0; mt < 2; ++mt) {
            const int row = m0 + wm + mt * 16 + rq;
            f32x4 v = acc[mt][nt];
#pragma unroll
            for (int e = 0; e < 4; ++e) {
                float val = v[e] + bv;
                if (flags & 1) val = fmaxf(val, 0.f);
                const size_t o = (size_t)(row + e) * N + col;
                if (resid) val += b2f(resid[o]);
                C[o] = f2b(val);
            }
        }
    }
}

// ---------------------------------------------------------------------------
// Block-level split-K GEMM (FFN2), register-prefetch staging.
// grid (M/64, N/128, 2); z = K-half; disjoint fp32 partials; kh==0 adds bias.
// ---------------------------------------------------------------------------
__global__ __launch_bounds__(256) void gemm_skk(
    const u16* __restrict__ A, const u16* __restrict__ Bt,
    const u16* __restrict__ bias, float* __restrict__ P,
    int M, int N, int Kfull)
{
    __shared__ u16 sA[2][64 * 32];
    __shared__ u16 sB[2][128 * 32];
    const int tid = threadIdx.x;
    const int wave = tid >> 6;
    const int lane = tid & 63;
    const int kh = blockIdx.z;
    const int Kh = Kfull >> 1;
    const int kb = kh * Kh;
    const int m0 = blockIdx.x * 64;
    const int n0 = blockIdx.y * 128;
    const int wm = (wave >> 1) * 32;
    const int wn = (wave & 1) * 64;

    const int lrow = lane >> 2;
    const int lcol = (lane & 3) * 8;
    const u16* gA = A + (size_t)(m0 + wave * 16 + lrow) * Kfull + kb + lcol;
    const u16* gB = Bt + (size_t)(n0 + wave * 32 + lrow) * Kfull + kb + lcol;
    const u16* gB2 = gB + (size_t)16 * Kfull;
    const int lofsA = wave * 16 * 32;
    const int lofsB = wave * 32 * 32;

    u16* dA0 = &sA[0][lofsA] + lane * 8;
    u16* dA1 = &sA[1][lofsA] + lane * 8;
    u16* dB0 = &sB[0][lofsB] + lane * 8;
    u16* dB1 = &sB[1][lofsB] + lane * 8;
    u16* dB2 = &sB[0][lofsB + 16 * 32] + lane * 8;
    u16* dB3 = &sB[1][lofsB + 16 * 32] + lane * 8;

    uint4 rA0 = *(const uint4*)(gA);
    uint4 rA1 = *(const uint4*)(gA + 32);
    uint4 rB0 = *(const uint4*)(gB);
    uint4 rB1 = *(const uint4*)(gB + 32);
    uint4 rB2 = *(const uint4*)(gB2);
    uint4 rB3 = *(const uint4*)(gB2 + 32);

    f32x4 acc[2][4];
#pragma unroll
    for (int i = 0; i < 2; ++i)
#pragma unroll
        for (int j = 0; j < 4; ++j) acc[i][j] = (f32x4){0.f, 0.f, 0.f, 0.f};

    const int q15 = lane & 15;
    const int koff = (lane >> 4) * 8;

    for (int k0 = 0; k0 < Kh; k0 += 64) {
        __syncthreads();
        *(uint4*)dA0 = rA0; *(uint4*)dA1 = rA1;
        *(uint4*)dB0 = rB0; *(uint4*)dB1 = rB1;
        *(uint4*)dB2 = rB2; *(uint4*)dB3 = rB3;
        __syncthreads();
        if (k0 < Kh - 64) {
            rA0 = *(const uint4*)(gA + k0 + 64);
            rA1 = *(const uint4*)(gA + k0 + 96);
            rB0 = *(const uint4*)(gB + k0 + 64);
            rB1 = *(const uint4*)(gB + k0 + 96);
            rB2 = *(const uint4*)(gB2 + k0 + 64);
            rB3 = *(const uint4*)(gB2 + k0 + 96);
        }
#pragma unroll 1
        for (int p = 0; p < 2; ++p) {
            bf16x8 af[2], bfr[4];
#pragma unroll
            for (int mt = 0; mt < 2; ++mt)
                af[mt] = *(const bf16x8*)(&sA[p][(wm + mt * 16 + q15) * 32 + koff]);
#pragma unroll
            for (int nt = 0; nt < 4; ++nt)
                bfr[nt] = *(const bf16x8*)(&sB[p][(wn + nt * 16 + q15) * 32 + koff]);
#pragma unroll
            for (int mt = 0; mt < 2; ++mt)
#pragma unroll
                for (int nt = 0; nt < 4; ++nt)
                    acc[mt][nt] = MFMA16(af[mt], bfr[nt], acc[mt][nt]);
        }
    }

    float* p = P + (size_t)kh * M * N;
    const int rq = (lane >> 4) * 4;
#pragma unroll
    for (int nt = 0; nt < 4; ++nt) {
        const int col = n0 + wn + nt * 16 + q15;
        const float bv = kh ? 0.f : b2f(bias[col]);
#pragma unroll
        for (int mt = 0; mt < 2; ++mt) {
            const int row = m0 + wm + mt * 16 + rq;
            f32x4 v = acc[mt][nt];
#pragma unroll
            for (int e = 0; e < 4; ++e)
                p[(size_t)(row + e) * N + col] = v[e] + bv;
        }
    }
}

// ---------------------------------------------------------------------------
// Flash attention (no mask). Q,K: [B*S, H*R]; Vt: [B,H,R,S]; O: [B*S, H*R].
// grid 1024, flat id = qt*64 + (b*16+h). Rows padded to 72 (2-way aliasing).
// l_i via MFMA against all-ones B (C-layout row = quad*4+e matches l_i[e]);
// sP write->read ordered by s_waitcnt lgkmcnt(0) (per-wave LDS region).
// ---------------------------------------------------------------------------
__global__ __launch_bounds__(256) void attn_k(
    const u16* __restrict__ Q, const u16* __restrict__ K,
    const u16* __restrict__ Vt, u16* __restrict__ O)
{
    __shared__ u16 sK[64 * 72];
    __shared__ u16 sV[64 * 72];
    __shared__ u16 sP[4][16 * 72];
    const int tid = threadIdx.x, wave = tid >> 6, lane = tid & 63;
    const int q15 = lane & 15, quad = lane >> 4;
    const int bid = blockIdx.x;
    const int g = bid & 63, qt = bid >> 6;
    const int h = g & 15, b = g >> 4;

    const u16* qb = Q + ((size_t)(b * 1024 + qt * 64 + wave * 16 + q15)) * 1024 + h * 64 + quad * 8;
    const bf16x8 qa0 = *(const bf16x8*)qb;
    const bf16x8 qa1 = *(const bf16x8*)(qb + 32);

    bf16x8 vone;
#pragma unroll
    for (int i = 0; i < 8; ++i) vone[i] = (__bf16)1.0f;

    f32x4 oacc[4];
#pragma unroll
    for (int i = 0; i < 4; ++i) oacc[i] = (f32x4){0.f, 0.f, 0.f, 0.f};
    f32x4 lacc = (f32x4){0.f, 0.f, 0.f, 0.f};

    const int srow = lane >> 3, scol8 = (lane & 7) * 8;
    const u16* kg = K + ((size_t)(b * 1024 + wave * 8 + srow)) * 1024 + h * 64 + scol8;
    const u16* vg = Vt + ((size_t)((b * 16 + h) * 64 + wave * 8 + srow)) * 1024 + scol8;
    u16* lKw = sK + (wave * 8 + srow) * 72 + scol8;
    u16* lVw = sV + (wave * 8 + srow) * 72 + scol8;

    uint4 k0r = *(const uint4*)kg;
    uint4 k1r = *(const uint4*)(kg + (size_t)32 * 1024);
    uint4 v0r = *(const uint4*)vg;
    uint4 v1r = *(const uint4*)(vg + (size_t)32 * 1024);

    for (int tt = 0; tt < 16; ++tt) {
        __syncthreads();
        *(uint4*)lKw = k0r;
        *(uint4*)(lKw + 32 * 72) = k1r;
        *(uint4*)lVw = v0r;
        *(uint4*)(lVw + 32 * 72) = v1r;
        __syncthreads();
        if (tt < 15) {
            const size_t t1 = (size_t)(tt + 1) * 64;
            k0r = *(const uint4*)(kg + t1 * 1024);
            k1r = *(const uint4*)(kg + t1 * 1024 + (size_t)32 * 1024);
            v0r = *(const uint4*)(vg + t1);
            v1r = *(const uint4*)(vg + t1 + (size_t)32 * 1024);
        }

        f32x4 sc[4];
#pragma unroll
        for (int nf = 0; nf < 4; ++nf) {
            bf16x8 kb0 = *(const bf16x8*)(sK + (nf * 16 + q15) * 72 + quad * 8);
            bf16x8 kb1 = *(const bf16x8*)(sK + (nf * 16 + q15) * 72 + 32 + quad * 8);
            f32x4 t = (f32x4){0.f, 0.f, 0.f, 0.f};
            t = MFMA16(qa0, kb0, t);
            t = MFMA16(qa1, kb1, t);
            sc[nf] = t * 0.125f;
        }
#pragma unroll
        for (int nf = 0; nf < 4; ++nf)
#pragma unroll
            for (int e = 0; e < 4; ++e) sc[nf][e] = __expf(fminf(sc[nf][e], 30.f));
#pragma unroll
        for (int nf = 0; nf < 4; ++nf)
#pragma unroll
            for (int e = 0; e < 4; ++e)
                sP[wave][(quad * 4 + e) * 72 + nf * 16 + q15] = f2b(sc[nf][e]);
        asm volatile("s_waitcnt lgkmcnt(0)" ::: "memory");
        const bf16x8 pa0 = *(const bf16x8*)(sP[wave] + q15 * 72 + quad * 8);
        const bf16x8 pa1 = *(const bf16x8*)(sP[wave] + q15 * 72 + 32 + quad * 8);
#pragma unroll
        for (int rf = 0; rf < 4; ++rf) {
            bf16x8 vb0 = *(const bf16x8*)(sV + (rf * 16 + q15) * 72 + quad * 8);
            bf16x8 vb1 = *(const bf16x8*)(sV + (rf * 16 + q15) * 72 + 32 + quad * 8);
            oacc[rf] = MFMA16(pa0, vb0, oacc[rf]);
            oacc[rf] = MFMA16(pa1, vb1, oacc[rf]);
        }
        lacc = MFMA16(pa0, vone, lacc);
        lacc = MFMA16(pa1, vone, lacc);
    }
#pragma unroll
    for (int rf = 0; rf < 4; ++rf)
#pragma unroll
        for (int e = 0; e < 4; ++e) {
            const float v = oacc[rf][e] / lacc[e];
            const size_t row = (size_t)(b * 1024 + qt * 64 + wave * 16 + quad * 4 + e);
            O[row * 1024 + h * 64 + rf * 16 + q15] = f2b(v);
        }
}

// ---------------------------------------------------------------------------
// LayerNorm over last dim (1024), eps=1e-3. One wave/row, 4 rows/block.
// ---------------------------------------------------------------------------
__global__ __launch_bounds__(256) void ln_k(
    const u16* __restrict__ y, const u16* __restrict__ g,
    const u16* __restrict__ be, void* __restrict__ out, const int* __restrict__ oflag)
{
    const int f = oflag ? *oflag : 0;
    const int tid = threadIdx.x, wave = tid >> 6, lane = tid & 63;
    const size_t row = (size_t)blockIdx.x * 4 + wave;
    const u16* p = y + row * 1024 + lane * 16;
    uint4 u0 = *(const uint4*)p;
    uint4 u1 = *(const uint4*)(p + 8);
    float v[16];
    unpack8(u0, v);
    unpack8(u1, v + 8);
    float s = 0.f, s2 = 0.f;
#pragma unroll
    for (int i = 0; i < 16; ++i) { s += v[i]; s2 += v[i] * v[i]; }
#pragma unroll
    for (int off = 1; off < 64; off <<= 1) {
        s += __shfl_xor(s, off, 64);
        s2 += __shfl_xor(s2, off, 64);
    }
    const float mean = s * (1.f / 1024.f);
    const float var = s2 * (1.f / 1024.f) - mean * mean;
    const float rstd = rsqrtf(var + 1e-3f);
    uint4 g0 = *(const uint4*)(g + lane * 16);
    uint4 g1 = *(const uint4*)(g + lane * 16 + 8);
    uint4 b0 = *(const uint4*)(be + lane * 16);
    uint4 b1 = *(const uint4*)(be + lane * 16 + 8);
    float gv[16], bv[16];
    unpack8(g0, gv); unpack8(g1, gv + 8);
    unpack8(b0, bv); unpack8(b1, bv + 8);
    float w[16];
#pragma unroll
    for (int i = 0; i < 16; ++i) w[i] = (v[i] - mean) * rstd * gv[i] + bv[i];
    if (f) {
        float* q = (float*)out + row * 1024 + lane * 16;
#pragma unroll
        for (int i = 0; i < 16; i += 4)
            *(float4*)(q + i) = make_float4(w[i], w[i + 1], w[i + 2], w[i + 3]);
    } else {
        uint4 o0, o1;
        o0.x = pack2(w[0], w[1]);   o0.y = pack2(w[2], w[3]);
        o0.z = pack2(w[4], w[5]);   o0.w = pack2(w[6], w[7]);
        o1.x = pack2(w[8], w[9]);   o1.y = pack2(w[10], w[11]);
        o1.z = pack2(w[12], w[13]); o1.w = pack2(w[14], w[15]);
        u16* q = (u16*)out + row * 1024 + lane * 16;
        *(uint4*)q = o0;
        *(uint4*)(q + 8) = o1;
    }
}

// ---------------------------------------------------------------------------
// Fused split-K reduce + residual + LayerNorm (FFN2 epilogue -> d_out).
// ---------------------------------------------------------------------------
__global__ __launch_bounds__(256) void ln3f_k(
    const float* __restrict__ p0, const float* __restrict__ p1,
    const u16* __restrict__ resid, const u16* __restrict__ g,
    const u16* __restrict__ be, void* __restrict__ out, const int* __restrict__ oflag)
{
    const int f = *oflag;
    const int tid = threadIdx.x, wave = tid >> 6, lane = tid & 63;
    const size_t row = (size_t)blockIdx.x * 4 + wave;
    const size_t base = row * 1024 + lane * 16;
    float v[16];
#pragma unroll
    for (int i = 0; i < 16; i += 4) {
        float4 a = *(const float4*)(p0 + base + i);
        float4 b = *(const float4*)(p1 + base + i);
        v[i + 0] = a.x + b.x; v[i + 1] = a.y + b.y;
        v[i + 2] = a.z + b.z; v[i + 3] = a.w + b.w;
    }
    uint4 r0 = *(const uint4*)(resid + base);
    uint4 r1 = *(const uint4*)(resid + base + 8);
    float rv[16];
    unpack8(r0, rv); unpack8(r1, rv + 8);
#pragma unroll
    for (int i = 0; i < 16; ++i) v[i] += rv[i];
    float s = 0.f, s2 = 0.f;
#pragma unroll
    for (int i = 0; i < 16; ++i) { s += v[i]; s2 += v[i] * v[i]; }
#pragma unroll
    for (int off = 1; off < 64; off <<= 1) {
        s += __shfl_xor(s, off, 64);
        s2 += __shfl_xor(s2, off, 64);
    }
    const float mean = s * (1.f / 1024.f);
    const float var = s2 * (1.f / 1024.f) - mean * mean;
    const float rstd = rsqrtf(var + 1e-3f);
    uint4 g0 = *(const uint4*)(g + lane * 16);
    uint4 g1 = *(const uint4*)(g + lane * 16 + 8);
    uint4 b0 = *(const uint4*)(be + lane * 16);
    uint4 b1 = *(const uint4*)(be + lane * 16 + 8);
    float gv[16], bv[16];
    unpack8(g0, gv); unpack8(g1, gv + 8);
    unpack8(b0, bv); unpack8(b1, bv + 8);
    float w[16];
#pragma unroll
    for (int i = 0; i < 16; ++i) w[i] = (v[i] - mean) * rstd * gv[i] + bv[i];
    if (f) {
        float* q = (float*)out + base;
#pragma unroll
        for (int i = 0; i < 16; i += 4)
            *(float4*)(q + i) = make_float4(w[i], w[i + 1], w[i + 2], w[i + 3]);
    } else {
        uint4 o0, o1;
        o0.x = pack2(w[0], w[1]);   o0.y = pack2(w[2], w[3]);
        o0.z = pack2(w[4], w[5]);   o0.w = pack2(w[6], w[7]);
        o1.x = pack2(w[8], w[9]);   o1.y = pack2(w[10], w[11]);
        o1.z = pack2(w[12], w[13]); o1.w = pack2(w[14], w[15]);
        u16* q = (u16*)out + base;
        *(uint4*)q = o0;
        *(uint4*)(q + 8) = o1;
    }
}

// ---------------------------------------------------------------------------
extern "C" void kernel_launch(void* const* d_in, const int* in_sizes, int n_in,
                              void* d_out, int out_size, void* d_ws, size_t ws_size,
                              hipStream_t stream)
{
    (void)in_sizes; (void)n_in; (void)out_size; (void)ws_size;
    const void* x   = d_in[0];
    const void* ctx = d_in[1];

    u16* ws = (u16*)d_ws;
    const size_t MEG = 1u << 20;
    u16* wT      = ws;               // 0..16M elems: transposed weights
    u16* bufx    = ws + 16 * MEG;
    u16* bufctx  = ws + 20 * MEG;
    u16* bufq    = ws + 24 * MEG;
    u16* bufk_sa = ws + 28 * MEG;
    u16* bufvt_sa= ws + 32 * MEG;
    u16* bufk_ca = ws + 36 * MEG;
    u16* bufvt_ca= ws + 40 * MEG;
    u16* bufo    = ws + 44 * MEG;
    u16* bufln   = ws + 48 * MEG;
    u16* small   = ws + 52 * MEG;
    int* flag    = (int*)(small + 20480);
    u16* bufh    = ws + 16 * MEG;    // FFN hidden (16..32M; bufx/ctx/q/k_sa dead)
    float* part  = (float*)(ws + 32 * MEG);  // 2x 4M f32 partials (32..48M; vt/kca/vtca/o dead)

    const int O_SABQ = 0,    O_SABK = 1024, O_SABV = 2048;
    const int O_CABK = 3072, O_CABV = 4096, O_CABQ = 5120;
    const int O_SABO = 6144, O_CABO = 7168;
    const int O_L1G = 8192,  O_L1B = 9216,  O_L2G = 10240, O_L2B = 11264;
    const int O_L3G = 12288, O_L3B = 13312, O_FB1 = 14336, O_FB2 = 18432;

    PtrTab tab;
    const void* sp[16] = { d_in[3], d_in[5], d_in[7], d_in[13], d_in[15], d_in[11],
                           d_in[9], d_in[17],
                           d_in[18], d_in[19], d_in[20], d_in[21], d_in[22], d_in[23],
                           d_in[25], d_in[27] };
    const int so[16] = { O_SABQ, O_SABK, O_SABV, O_CABK, O_CABV, O_CABQ, O_SABO, O_CABO,
                         O_L1G, O_L1B, O_L2G, O_L2B, O_L3G, O_L3B, O_FB1, O_FB2 };
    const int sc[16] = { 1024, 1024, 1024, 1024, 1024, 1024, 1024, 1024,
                         1024, 1024, 1024, 1024, 1024, 1024, 4096, 1024 };
    for (int i = 0; i < 16; ++i) { tab.p[i] = sp[i]; tab.off[i] = so[i]; tab.cnt[i] = sc[i]; }

    PtrTab tab6;
    const void* wp[6] = { d_in[2], d_in[4], d_in[6], d_in[12], d_in[14], d_in[10] };
    for (int i = 0; i < 6; ++i) tab6.p[i] = wp[i];

    const dim3 blk(256);
    const dim3 gN1(64, 8);

    // ---- dtype normalize + weight prep (R6-verified chain) ----
    detect_k<<<1, blk, 0, stream>>>((const u32*)x, flag);
    conv2_k<<<dim3(2048, 2), blk, 0, stream>>>(x, ctx, bufx, bufctx, 4 * MEG, flag);
    conv_small_k<<<dim3(16), blk, 0, stream>>>(tab, small, flag);
    transpose6_k<<<dim3(1, 16, 96), blk, 0, stream>>>(tab6, wT, flag);
    transpose_k<<<dim3(16, 16), blk, 0, stream>>>(d_in[8],  wT + 6 * MEG, 1024, 1024, flag);
    transpose_k<<<dim3(16, 16), blk, 0, stream>>>(d_in[16], wT + 7 * MEG, 1024, 1024, flag);
    transpose_k<<<dim3(64, 16), blk, 0, stream>>>(d_in[24], wT + 8 * MEG, 1024, 4096, flag);
    transpose_k<<<dim3(16, 64), blk, 0, stream>>>(d_in[26], wT + 12 * MEG, 4096, 1024, flag);

    // ---- fused projections ----
    gemm_qkv_k<<<dim3(40, 32), blk, 0, stream>>>(bufx, bufctx, wT, small,
                                                 bufq, bufk_sa, bufvt_sa, bufk_ca, bufvt_ca);

    // ---- self-attention ----
    attn_k<<<dim3(1024), blk, 0, stream>>>(bufq, bufk_sa, bufvt_sa, bufo);
    gemm_n1k<<<gN1, blk, 0, stream>>>(bufo, wT + 6 * MEG, small + O_SABO, bufx,
                                      bufq, 4096, 1024, 1024, 0);
    ln_k<<<dim3(1024), blk, 0, stream>>>(bufq, small + O_L1G, small + O_L1B, bufln, nullptr);

    // ---- cross-attention ----
    gemm_n1k<<<gN1, blk, 0, stream>>>(bufln, wT + 5 * MEG, small + O_CABQ, nullptr,
                                      bufq, 4096, 1024, 1024, 0);
    attn_k<<<dim3(1024), blk, 0, stream>>>(bufq, bufk_ca, bufvt_ca, bufo);
    gemm_n1k<<<gN1, blk, 0, stream>>>(bufo, wT + 7 * MEG, small + O_CABO, bufln,
                                      bufq, 4096, 1024, 1024, 0);
    ln_k<<<dim3(1024), blk, 0, stream>>>(bufq, small + O_L2G, small + O_L2B, bufln, nullptr);

    // ---- FFN ----
    gemm_bt<<<dim3(32, 32), blk, 0, stream>>>(bufln, wT + 8 * MEG, small + O_FB1, nullptr,
                                              bufh, 4096, 4096, 1024, 1);
    gemm_skk<<<dim3(64, 8, 2), blk, 0, stream>>>(bufh, wT + 12 * MEG, small + O_FB2, part,
                                                 4096, 1024, 4096);
    ln3f_k<<<dim3(1024), blk, 0, stream>>>(part, part + (size_t)4 * MEG, bufln,
                                           small + O_L3G, small + O_L3B, d_out, flag);
}

// Round 11
// 515.160 us; speedup vs baseline: 1.0093x; 1.0093x over previous
//
#include <hip/hip_runtime.h>
#include <math.h>

typedef unsigned short u16;
typedef unsigned int u32;
typedef __bf16 bf16x8 __attribute__((ext_vector_type(8)));
typedef float f32x4 __attribute__((ext_vector_type(4)));

#define MFMA16(a, b, c) __builtin_amdgcn_mfma_f32_16x16x32_bf16(a, b, c, 0, 0, 0)

// QSCALE = (1/sqrt(64)) * log2(e): folded into Q at projection time so the
// attention inner loop needs only v_exp_f32 (2^x) — no scale/clamp/log2e mul.
#define QSCALE 0.1803368801111204f

typedef __attribute__((address_space(1))) void gvoid;
typedef __attribute__((address_space(3))) void lvoid;

__device__ __forceinline__ void gload_lds16(const void* g, void* l) {
    __builtin_amdgcn_global_load_lds((gvoid*)g, (lvoid*)l, 16, 0, 0);
}

__device__ __forceinline__ float fexp2(float x) {
#if __has_builtin(__builtin_amdgcn_exp2f)
    return __builtin_amdgcn_exp2f(x);
#else
    return __expf(x * 0.6931471805599453f);
#endif
}

__device__ __forceinline__ float b2f(u16 u) {
    union { u32 i; float f; } w;
    w.i = ((u32)u) << 16;
    return w.f;
}

__device__ __forceinline__ u16 f2b(float f) {
    union { float f; u32 i; } w;
    w.f = f;
    u32 x = w.i;
    u32 r = (x + 0x7fffu + ((x >> 16) & 1u)) >> 16;  // RNE
    return (u16)r;
}

__device__ __forceinline__ void unpack8(uint4 u, float* v) {
    v[0] = b2f((u16)(u.x & 0xffff)); v[1] = b2f((u16)(u.x >> 16));
    v[2] = b2f((u16)(u.y & 0xffff)); v[3] = b2f((u16)(u.y >> 16));
    v[4] = b2f((u16)(u.z & 0xffff)); v[5] = b2f((u16)(u.z >> 16));
    v[6] = b2f((u16)(u.w & 0xffff)); v[7] = b2f((u16)(u.w >> 16));
}

__device__ __forceinline__ u32 pack2(float a, float b) {
    return (u32)f2b(a) | ((u32)f2b(b) << 16);
}

// ---------------------------------------------------------------------------
// Input dtype detector: flag=1 -> fp32 inputs (verified in R2).
// ---------------------------------------------------------------------------
__global__ __launch_bounds__(256) void detect_k(const u32* __restrict__ x, int* __restrict__ flag)
{
    __shared__ int cnt[256];
    int c = 0;
#pragma unroll 4
    for (int i = 0; i < 256; ++i) {
        const u32 w = x[threadIdx.x * 256 + i];
        const u32 e = (w >> 7) & 0xFF;
        c += (e < 0x20 || e > 0x4F) ? 1 : 0;
    }
    cnt[threadIdx.x] = c;
    __syncthreads();
    if (threadIdx.x == 0) {
        int t = 0;
        for (int i = 0; i < 256; ++i) t += cnt[i];
        *flag = (t > 16384) ? 1 : 0;
    }
}

// Convert x and context in one dispatch: blockIdx.y selects tensor.
__global__ __launch_bounds__(256) void conv2_k(
    const void* __restrict__ a, const void* __restrict__ b,
    u16* __restrict__ oa, u16* __restrict__ ob, int n, const int* __restrict__ flag)
{
    const int f = *flag;
    const void* in = blockIdx.y ? b : a;
    u16* out = blockIdx.y ? ob : oa;
    const int i = (blockIdx.x * 256 + threadIdx.x) * 8;
    if (i >= n) return;
    if (f) {
        const float* p = (const float*)in + i;
        uint4 o;
        o.x = pack2(p[0], p[1]); o.y = pack2(p[2], p[3]);
        o.z = pack2(p[4], p[5]); o.w = pack2(p[6], p[7]);
        *(uint4*)(out + i) = o;
    } else {
        *(uint4*)(out + i) = *(const uint4*)((const u16*)in + i);
    }
}

struct PtrTab {
    const void* p[16];
    int off[16];
    int cnt[16];
};

__global__ __launch_bounds__(256) void conv_small_k(
    PtrTab t, u16* __restrict__ out, const int* __restrict__ flag)
{
    const int f = *flag;
    const void* src = t.p[blockIdx.x];
    const int n = t.cnt[blockIdx.x];
    u16* dst = out + t.off[blockIdx.x];
    for (int i = threadIdx.x; i < n; i += 256)
        dst[i] = f ? f2b(((const float*)src)[i]) : ((const u16*)src)[i];
}

// ---------------------------------------------------------------------------
// Generic transpose: in [rows][cols] -> out bf16 [cols][rows].
// ---------------------------------------------------------------------------
__global__ __launch_bounds__(256) void transpose_k(
    const void* __restrict__ in, u16* __restrict__ out, int rows, int cols,
    const int* __restrict__ flag)
{
    const int f = *flag;
    __shared__ u16 t[64][65];
    const int tid = threadIdx.x;
    const int lr = tid >> 4;
    const int lc = (tid & 15) * 4;
    const int r0 = blockIdx.y * 64, c0 = blockIdx.x * 64;
#pragma unroll
    for (int i = 0; i < 4; ++i) {
        const size_t off = (size_t)(r0 + i * 16 + lr) * cols + c0 + lc;
        if (f) {
            const float* p = (const float*)in + off;
            t[i * 16 + lr][lc + 0] = f2b(p[0]);
            t[i * 16 + lr][lc + 1] = f2b(p[1]);
            t[i * 16 + lr][lc + 2] = f2b(p[2]);
            t[i * 16 + lr][lc + 3] = f2b(p[3]);
        } else {
            const u16* p = (const u16*)in + off;
            t[i * 16 + lr][lc + 0] = p[0];
            t[i * 16 + lr][lc + 1] = p[1];
            t[i * 16 + lr][lc + 2] = p[2];
            t[i * 16 + lr][lc + 3] = p[3];
        }
    }
    __syncthreads();
#pragma unroll
    for (int i = 0; i < 4; ++i) {
        const int rr = i * 16 + lr;
        uint2 o;
        o.x = (u32)t[lc + 0][rr] | ((u32)t[lc + 1][rr] << 16);
        o.y = (u32)t[lc + 2][rr] | ((u32)t[lc + 3][rr] << 16);
        *(uint2*)(out + (size_t)(c0 + rr) * rows + r0 + lc) = o;
    }
}

// ---------------------------------------------------------------------------
// Fused transpose of the 6 head-blocked weights [16,1024,64] -> [1024,1024].
// grid (1, 16, 96): z = w*16 + h.
// ---------------------------------------------------------------------------
__global__ __launch_bounds__(256) void transpose6_k(
    PtrTab tab, u16* __restrict__ wT, const int* __restrict__ flag)
{
    const int f = *flag;
    __shared__ u16 t[64][65];
    const int tid = threadIdx.x;
    const int lr = tid >> 4;
    const int lc = (tid & 15) * 4;
    const int w = blockIdx.z >> 4, h = blockIdx.z & 15;
    const void* in = tab.p[w];
    u16* out = wT + (size_t)w * (1u << 20) + h * 65536;
    const size_t ibase = (size_t)h * 65536;
    const int r0 = blockIdx.y * 64;
#pragma unroll
    for (int i = 0; i < 4; ++i) {
        const size_t off = ibase + (size_t)(r0 + i * 16 + lr) * 64 + lc;
        if (f) {
            const float* p = (const float*)in + off;
            t[i * 16 + lr][lc + 0] = f2b(p[0]);
            t[i * 16 + lr][lc + 1] = f2b(p[1]);
            t[i * 16 + lr][lc + 2] = f2b(p[2]);
            t[i * 16 + lr][lc + 3] = f2b(p[3]);
        } else {
            const u16* p = (const u16*)in + off;
            t[i * 16 + lr][lc + 0] = p[0];
            t[i * 16 + lr][lc + 1] = p[1];
            t[i * 16 + lr][lc + 2] = p[2];
            t[i * 16 + lr][lc + 3] = p[3];
        }
    }
    __syncthreads();
#pragma unroll
    for (int i = 0; i < 4; ++i) {
        const int rr = i * 16 + lr;
        uint2 o;
        o.x = (u32)t[lc + 0][rr] | ((u32)t[lc + 1][rr] << 16);
        o.y = (u32)t[lc + 2][rr] | ((u32)t[lc + 3][rr] << 16);
        *(uint2*)(out + (size_t)rr * 1024 + r0 + lc) = o;
    }
}

// ---------------------------------------------------------------------------
// Grouped projection GEMM, BK=64 panelized, register-prefetch staging (kept:
// measured 59.6 vs 60.2 us for gload). SA-Q/K/V (A=x) + CA-K/V (A=ctx).
// M=4096, K=1024. grid (40, 32). SA-Q output pre-scaled by QSCALE (fp32).
// ---------------------------------------------------------------------------
__global__ __launch_bounds__(256) void gemm_qkv_k(
    const u16* __restrict__ X, const u16* __restrict__ CTX,
    const u16* __restrict__ wT, const u16* __restrict__ bias,
    u16* __restrict__ Qo, u16* __restrict__ Ksa, u16* __restrict__ Vsa,
    u16* __restrict__ Kca, u16* __restrict__ Vca)
{
    __shared__ u16 sA[2][128 * 32];
    __shared__ u16 sB[2][128 * 32];
    const int tid = threadIdx.x;
    const int wave = tid >> 6;
    const int lane = tid & 63;
    const int bx = blockIdx.x;
    const int seg = bx >> 3, c8 = bx & 7;
    const int m0 = blockIdx.y * 128;
    const int wm = (wave >> 1) * 64;
    const int wn = (wave & 1) * 64;
    const u16* A = (seg < 3) ? X : CTX;

    const int lrow = lane >> 2;
    const int lcol = (lane & 3) * 8;
    const u16* gA = A + (size_t)(m0 + wave * 16 + lrow) * 1024 + lcol;
    const u16* gB = wT + (size_t)(bx * 128 + wave * 16 + lrow) * 1024 + lcol;
    const int lofs = wave * 16 * 32;

    u16* dA0 = &sA[0][lofs] + lane * 8;
    u16* dA1 = &sA[1][lofs] + lane * 8;
    u16* dA2 = &sA[0][64 * 32 + lofs] + lane * 8;
    u16* dA3 = &sA[1][64 * 32 + lofs] + lane * 8;
    u16* dB0 = &sB[0][lofs] + lane * 8;
    u16* dB1 = &sB[1][lofs] + lane * 8;
    u16* dB2 = &sB[0][64 * 32 + lofs] + lane * 8;
    u16* dB3 = &sB[1][64 * 32 + lofs] + lane * 8;

    uint4 rA0 = *(const uint4*)(gA);
    uint4 rA1 = *(const uint4*)(gA + 32);
    uint4 rA2 = *(const uint4*)(gA + (size_t)64 * 1024);
    uint4 rA3 = *(const uint4*)(gA + (size_t)64 * 1024 + 32);
    uint4 rB0 = *(const uint4*)(gB);
    uint4 rB1 = *(const uint4*)(gB + 32);
    uint4 rB2 = *(const uint4*)(gB + (size_t)64 * 1024);
    uint4 rB3 = *(const uint4*)(gB + (size_t)64 * 1024 + 32);

    f32x4 acc[4][4];
#pragma unroll
    for (int i = 0; i < 4; ++i)
#pragma unroll
        for (int j = 0; j < 4; ++j) acc[i][j] = (f32x4){0.f, 0.f, 0.f, 0.f};

    const int q15 = lane & 15;
    const int koff = (lane >> 4) * 8;

    for (int k0 = 0; k0 < 1024; k0 += 64) {
        __syncthreads();
        *(uint4*)dA0 = rA0; *(uint4*)dA1 = rA1;
        *(uint4*)dA2 = rA2; *(uint4*)dA3 = rA3;
        *(uint4*)dB0 = rB0; *(uint4*)dB1 = rB1;
        *(uint4*)dB2 = rB2; *(uint4*)dB3 = rB3;
        __syncthreads();
        if (k0 < 1024 - 64) {
            rA0 = *(const uint4*)(gA + k0 + 64);
            rA1 = *(const uint4*)(gA + k0 + 96);
            rA2 = *(const uint4*)(gA + (size_t)64 * 1024 + k0 + 64);
            rA3 = *(const uint4*)(gA + (size_t)64 * 1024 + k0 + 96);
            rB0 = *(const uint4*)(gB + k0 + 64);
            rB1 = *(const uint4*)(gB + k0 + 96);
            rB2 = *(const uint4*)(gB + (size_t)64 * 1024 + k0 + 64);
            rB3 = *(const uint4*)(gB + (size_t)64 * 1024 + k0 + 96);
        }
#pragma unroll 1
        for (int p = 0; p < 2; ++p) {
            bf16x8 af[4], bfr[4];
#pragma unroll
            for (int mt = 0; mt < 4; ++mt)
                af[mt] = *(const bf16x8*)(&sA[p][(wm + mt * 16 + q15) * 32 + koff]);
#pragma unroll
            for (int nt = 0; nt < 4; ++nt)
                bfr[nt] = *(const bf16x8*)(&sB[p][(wn + nt * 16 + q15) * 32 + koff]);
#pragma unroll
            for (int mt = 0; mt < 4; ++mt)
#pragma unroll
                for (int nt = 0; nt < 4; ++nt)
                    acc[mt][nt] = MFMA16(af[mt], bfr[nt], acc[mt][nt]);
        }
    }

    u16* outp;
    int vt;
    switch (seg) {
        case 0: outp = Qo;  vt = 0; break;
        case 1: outp = Ksa; vt = 0; break;
        case 2: outp = Vsa; vt = 1; break;
        case 3: outp = Kca; vt = 0; break;
        default: outp = Vca; vt = 1; break;
    }
    const float qs = (seg == 0) ? QSCALE : 1.0f;
    const int rq = (lane >> 4) * 4;
#pragma unroll
    for (int nt = 0; nt < 4; ++nt) {
        const int col = c8 * 128 + wn + nt * 16 + q15;
        const float bv = b2f(bias[bx * 128 + wn + nt * 16 + q15]);
#pragma unroll
        for (int mt = 0; mt < 4; ++mt) {
            const int row = m0 + wm + mt * 16 + rq;
            f32x4 v = acc[mt][nt];
            if (vt) {
                const int bb = row >> 10, tt = row & 1023;
                const int hh = col >> 6, rr = col & 63;
                const size_t idx = ((((size_t)bb * 16 + hh) * 64 + rr) << 10) + tt;
                uint2 o;
                o.x = pack2(v[0] + bv, v[1] + bv);
                o.y = pack2(v[2] + bv, v[3] + bv);
                *(uint2*)(outp + idx) = o;
            } else {
#pragma unroll
                for (int e = 0; e < 4; ++e)
                    outp[(size_t)(row + e) * 1024 + col] = f2b((v[e] + bv) * qs);
            }
        }
    }
}

// ---------------------------------------------------------------------------
// GEMM 128x128 tile, BK=64 panelized, global_load_lds staging (R8-verified;
// R10's reg-staging was neutral-to-negative here). FFN1. grid (N/128, M/128).
// ---------------------------------------------------------------------------
__global__ __launch_bounds__(256) void gemm_bt(
    const u16* __restrict__ A, const u16* __restrict__ Bt,
    const u16* __restrict__ bias, const u16* __restrict__ resid,
    u16* __restrict__ C, int M, int N, int K, int flags)
{
    __shared__ u16 sA[2][128 * 32];
    __shared__ u16 sB[2][128 * 32];
    const int tid = threadIdx.x;
    const int wave = tid >> 6;
    const int lane = tid & 63;
    const int m0 = blockIdx.y * 128;
    const int n0 = blockIdx.x * 128;
    const int wm = (wave >> 1) * 64;
    const int wn = (wave & 1) * 64;

    const int lrow = lane >> 2;
    const int lcol = (lane & 3) * 8;
    const u16* gA = A + (size_t)(m0 + wave * 16 + lrow) * K + lcol;
    const u16* gB = Bt + (size_t)(n0 + wave * 16 + lrow) * K + lcol;
    const int lofs = wave * 16 * 32;

    f32x4 acc[4][4];
#pragma unroll
    for (int i = 0; i < 4; ++i)
#pragma unroll
        for (int j = 0; j < 4; ++j) acc[i][j] = (f32x4){0.f, 0.f, 0.f, 0.f};

    const int q15 = lane & 15;
    const int koff = (lane >> 4) * 8;

    for (int k0 = 0; k0 < K; k0 += 64) {
        __syncthreads();
        gload_lds16(gA + k0,      &sA[0][lofs]);
        gload_lds16(gA + k0 + 32, &sA[1][lofs]);
        gload_lds16(gA + (size_t)64 * K + k0,      &sA[0][64 * 32 + lofs]);
        gload_lds16(gA + (size_t)64 * K + k0 + 32, &sA[1][64 * 32 + lofs]);
        gload_lds16(gB + k0,      &sB[0][lofs]);
        gload_lds16(gB + k0 + 32, &sB[1][lofs]);
        gload_lds16(gB + (size_t)64 * K + k0,      &sB[0][64 * 32 + lofs]);
        gload_lds16(gB + (size_t)64 * K + k0 + 32, &sB[1][64 * 32 + lofs]);
        __syncthreads();
#pragma unroll 1
        for (int p = 0; p < 2; ++p) {
            bf16x8 af[4], bfr[4];
#pragma unroll
            for (int mt = 0; mt < 4; ++mt)
                af[mt] = *(const bf16x8*)(&sA[p][(wm + mt * 16 + q15) * 32 + koff]);
#pragma unroll
            for (int nt = 0; nt < 4; ++nt)
                bfr[nt] = *(const bf16x8*)(&sB[p][(wn + nt * 16 + q15) * 32 + koff]);
#pragma unroll
            for (int mt = 0; mt < 4; ++mt)
#pragma unroll
                for (int nt = 0; nt < 4; ++nt)
                    acc[mt][nt] = MFMA16(af[mt], bfr[nt], acc[mt][nt]);
        }
    }

    const int rq = (lane >> 4) * 4;
#pragma unroll
    for (int nt = 0; nt < 4; ++nt) {
        const int col = n0 + wn + nt * 16 + q15;
        const float bv = b2f(bias[col]);
#pragma unroll
        for (int mt = 0; mt < 4; ++mt) {
            const int row = m0 + wm + mt * 16 + rq;
            f32x4 v = acc[mt][nt];
#pragma unroll
            for (int e = 0; e < 4; ++e) {
                float val = v[e] + bv;
                if (flags & 1) val = fmaxf(val, 0.f);
                const size_t o = (size_t)(row + e) * N + col;
                if (resid) val += b2f(resid[o]);
                C[o] = f2b(val);
            }
        }
    }
}

// ---------------------------------------------------------------------------
// GEMM 64x128 tile, BK=64 panelized, global_load_lds staging (R8-verified).
// N=1024 shapes (K=1024). grid (M/64, 8). flags: 1=relu, 4=scale by QSCALE.
// ---------------------------------------------------------------------------
__global__ __launch_bounds__(256) void gemm_n1k(
    const u16* __restrict__ A, const u16* __restrict__ Bt,
    const u16* __restrict__ bias, const u16* __restrict__ resid,
    u16* __restrict__ C, int M, int N, int K, int flags)
{
    __shared__ u16 sA[2][64 * 32];
    __shared__ u16 sB[2][128 * 32];
    const int tid = threadIdx.x;
    const int wave = tid >> 6;
    const int lane = tid & 63;
    const int m0 = blockIdx.x * 64;
    const int n0 = blockIdx.y * 128;
    const int wm = (wave >> 1) * 32;
    const int wn = (wave & 1) * 64;

    const int lrow = lane >> 2;
    const int lcol = (lane & 3) * 8;
    const u16* gA = A + (size_t)(m0 + wave * 16 + lrow) * K + lcol;
    const u16* gB = Bt + (size_t)(n0 + wave * 32 + lrow) * K + lcol;
    const u16* gB2 = gB + (size_t)16 * K;
    const int lofsA = wave * 16 * 32;
    const int lofsB = wave * 32 * 32;

    f32x4 acc[2][4];
#pragma unroll
    for (int i = 0; i < 2; ++i)
#pragma unroll
        for (int j = 0; j < 4; ++j) acc[i][j] = (f32x4){0.f, 0.f, 0.f, 0.f};

    const int q15 = lane & 15;
    const int koff = (lane >> 4) * 8;

    for (int k0 = 0; k0 < K; k0 += 64) {
        __syncthreads();
        gload_lds16(gA + k0,      &sA[0][lofsA]);
        gload_lds16(gA + k0 + 32, &sA[1][lofsA]);
        gload_lds16(gB + k0,       &sB[0][lofsB]);
        gload_lds16(gB + k0 + 32,  &sB[1][lofsB]);
        gload_lds16(gB2 + k0,      &sB[0][lofsB + 16 * 32]);
        gload_lds16(gB2 + k0 + 32, &sB[1][lofsB + 16 * 32]);
        __syncthreads();
#pragma unroll 1
        for (int p = 0; p < 2; ++p) {
            bf16x8 af[2], bfr[4];
#pragma unroll
            for (int mt = 0; mt < 2; ++mt)
                af[mt] = *(const bf16x8*)(&sA[p][(wm + mt * 16 + q15) * 32 + koff]);
#pragma unroll
            for (int nt = 0; nt < 4; ++nt)
                bfr[nt] = *(const bf16x8*)(&sB[p][(wn + nt * 16 + q15) * 32 + koff]);
#pragma unroll
            for (int mt = 0; mt < 2; ++mt)
#pragma unroll
                for (int nt = 0; nt < 4; ++nt)
                    acc[mt][nt] = MFMA16(af[mt], bfr[nt], acc[mt][nt]);
        }
    }

    const int rq = (lane >> 4) * 4;
#pragma unroll
    for (int nt = 0; nt < 4; ++nt) {
        const int col = n0 + wn + nt * 16 + q15;
        const float bv = b2f(bias[col]);
#pragma unroll
        for (int mt = 0; mt < 2; ++mt) {
            const int row = m0 + wm + mt * 16 + rq;
            f32x4 v = acc[mt][nt];
#pragma unroll
            for (int e = 0; e < 4; ++e) {
                float val = v[e] + bv;
                if (flags & 1) val = fmaxf(val, 0.f);
                if (flags & 4) val *= QSCALE;
                const size_t o = (size_t)(row + e) * N + col;
                if (resid) val += b2f(resid[o]);
                C[o] = f2b(val);
            }
        }
    }
}

// ---------------------------------------------------------------------------
// Block-level split-K GEMM (FFN2), global_load_lds staging (R8-verified).
// grid (M/64, N/128, 2); z = K-half; disjoint fp32 partials; kh==0 adds bias.
// ---------------------------------------------------------------------------
__global__ __launch_bounds__(256) void gemm_skk(
    const u16* __restrict__ A, const u16* __restrict__ Bt,
    const u16* __restrict__ bias, float* __restrict__ P,
    int M, int N, int Kfull)
{
    __shared__ u16 sA[2][64 * 32];
    __shared__ u16 sB[2][128 * 32];
    const int tid = threadIdx.x;
    const int wave = tid >> 6;
    const int lane = tid & 63;
    const int kh = blockIdx.z;
    const int Kh = Kfull >> 1;
    const int kb = kh * Kh;
    const int m0 = blockIdx.x * 64;
    const int n0 = blockIdx.y * 128;
    const int wm = (wave >> 1) * 32;
    const int wn = (wave & 1) * 64;

    const int lrow = lane >> 2;
    const int lcol = (lane & 3) * 8;
    const u16* gA = A + (size_t)(m0 + wave * 16 + lrow) * Kfull + kb + lcol;
    const u16* gB = Bt + (size_t)(n0 + wave * 32 + lrow) * Kfull + kb + lcol;
    const u16* gB2 = gB + (size_t)16 * Kfull;
    const int lofsA = wave * 16 * 32;
    const int lofsB = wave * 32 * 32;

    f32x4 acc[2][4];
#pragma unroll
    for (int i = 0; i < 2; ++i)
#pragma unroll
        for (int j = 0; j < 4; ++j) acc[i][j] = (f32x4){0.f, 0.f, 0.f, 0.f};

    const int q15 = lane & 15;
    const int koff = (lane >> 4) * 8;

    for (int k0 = 0; k0 < Kh; k0 += 64) {
        __syncthreads();
        gload_lds16(gA + k0,      &sA[0][lofsA]);
        gload_lds16(gA + k0 + 32, &sA[1][lofsA]);
        gload_lds16(gB + k0,       &sB[0][lofsB]);
        gload_lds16(gB + k0 + 32,  &sB[1][lofsB]);
        gload_lds16(gB2 + k0,      &sB[0][lofsB + 16 * 32]);
        gload_lds16(gB2 + k0 + 32, &sB[1][lofsB + 16 * 32]);
        __syncthreads();
#pragma unroll 1
        for (int p = 0; p < 2; ++p) {
            bf16x8 af[2], bfr[4];
#pragma unroll
            for (int mt = 0; mt < 2; ++mt)
                af[mt] = *(const bf16x8*)(&sA[p][(wm + mt * 16 + q15) * 32 + koff]);
#pragma unroll
            for (int nt = 0; nt < 4; ++nt)
                bfr[nt] = *(const bf16x8*)(&sB[p][(wn + nt * 16 + q15) * 32 + koff]);
#pragma unroll
            for (int mt = 0; mt < 2; ++mt)
#pragma unroll
                for (int nt = 0; nt < 4; ++nt)
                    acc[mt][nt] = MFMA16(af[mt], bfr[nt], acc[mt][nt]);
        }
    }

    float* p = P + (size_t)kh * M * N;
    const int rq = (lane >> 4) * 4;
#pragma unroll
    for (int nt = 0; nt < 4; ++nt) {
        const int col = n0 + wn + nt * 16 + q15;
        const float bv = kh ? 0.f : b2f(bias[col]);
#pragma unroll
        for (int mt = 0; mt < 2; ++mt) {
            const int row = m0 + wm + mt * 16 + rq;
            f32x4 v = acc[mt][nt];
#pragma unroll
            for (int e = 0; e < 4; ++e)
                p[(size_t)(row + e) * N + col] = v[e] + bv;
        }
    }
}

// ---------------------------------------------------------------------------
// Flash attention (no mask). Q,K: [B*S, H*R]; Vt: [B,H,R,S]; O: [B*S, H*R].
// grid 1024, flat id = qt*64 + (b*16+h). Rows padded to 72 (2-way aliasing).
// Q is pre-scaled by QSCALE at projection time, so P = exp2(QK) directly —
// inner loop has only v_exp_f32 (no scale/clamp/log2e mul). l_i via MFMA
// against all-ones B; sP write->read ordered by s_waitcnt lgkmcnt(0).
// ---------------------------------------------------------------------------
__global__ __launch_bounds__(256) void attn_k(
    const u16* __restrict__ Q, const u16* __restrict__ K,
    const u16* __restrict__ Vt, u16* __restrict__ O)
{
    __shared__ u16 sK[64 * 72];
    __shared__ u16 sV[64 * 72];
    __shared__ u16 sP[4][16 * 72];
    const int tid = threadIdx.x, wave = tid >> 6, lane = tid & 63;
    const int q15 = lane & 15, quad = lane >> 4;
    const int bid = blockIdx.x;
    const int g = bid & 63, qt = bid >> 6;
    const int h = g & 15, b = g >> 4;

    const u16* qb = Q + ((size_t)(b * 1024 + qt * 64 + wave * 16 + q15)) * 1024 + h * 64 + quad * 8;
    const bf16x8 qa0 = *(const bf16x8*)qb;
    const bf16x8 qa1 = *(const bf16x8*)(qb + 32);

    bf16x8 vone;
#pragma unroll
    for (int i = 0; i < 8; ++i) vone[i] = (__bf16)1.0f;

    f32x4 oacc[4];
#pragma unroll
    for (int i = 0; i < 4; ++i) oacc[i] = (f32x4){0.f, 0.f, 0.f, 0.f};
    f32x4 lacc = (f32x4){0.f, 0.f, 0.f, 0.f};

    const int srow = lane >> 3, scol8 = (lane & 7) * 8;
    const u16* kg = K + ((size_t)(b * 1024 + wave * 8 + srow)) * 1024 + h * 64 + scol8;
    const u16* vg = Vt + ((size_t)((b * 16 + h) * 64 + wave * 8 + srow)) * 1024 + scol8;
    u16* lKw = sK + (wave * 8 + srow) * 72 + scol8;
    u16* lVw = sV + (wave * 8 + srow) * 72 + scol8;

    uint4 k0r = *(const uint4*)kg;
    uint4 k1r = *(const uint4*)(kg + (size_t)32 * 1024);
    uint4 v0r = *(const uint4*)vg;
    uint4 v1r = *(const uint4*)(vg + (size_t)32 * 1024);

    for (int tt = 0; tt < 16; ++tt) {
        __syncthreads();
        *(uint4*)lKw = k0r;
        *(uint4*)(lKw + 32 * 72) = k1r;
        *(uint4*)lVw = v0r;
        *(uint4*)(lVw + 32 * 72) = v1r;
        __syncthreads();
        if (tt < 15) {
            const size_t t1 = (size_t)(tt + 1) * 64;
            k0r = *(const uint4*)(kg + t1 * 1024);
            k1r = *(const uint4*)(kg + t1 * 1024 + (size_t)32 * 1024);
            v0r = *(const uint4*)(vg + t1);
            v1r = *(const uint4*)(vg + t1 + (size_t)32 * 1024);
        }

        f32x4 sc[4];
#pragma unroll
        for (int nf = 0; nf < 4; ++nf) {
            bf16x8 kb0 = *(const bf16x8*)(sK + (nf * 16 + q15) * 72 + quad * 8);
            bf16x8 kb1 = *(const bf16x8*)(sK + (nf * 16 + q15) * 72 + 32 + quad * 8);
            f32x4 t = (f32x4){0.f, 0.f, 0.f, 0.f};
            t = MFMA16(qa0, kb0, t);
            t = MFMA16(qa1, kb1, t);
            sc[nf] = t;
        }
#pragma unroll
        for (int nf = 0; nf < 4; ++nf)
#pragma unroll
            for (int e = 0; e < 4; ++e) sc[nf][e] = fexp2(sc[nf][e]);
#pragma unroll
        for (int nf = 0; nf < 4; ++nf)
#pragma unroll
            for (int e = 0; e < 4; ++e)
                sP[wave][(quad * 4 + e) * 72 + nf * 16 + q15] = f2b(sc[nf][e]);
        asm volatile("s_waitcnt lgkmcnt(0)" ::: "memory");
        const bf16x8 pa0 = *(const bf16x8*)(sP[wave] + q15 * 72 + quad * 8);
        const bf16x8 pa1 = *(const bf16x8*)(sP[wave] + q15 * 72 + 32 + quad * 8);
#pragma unroll
        for (int rf = 0; rf < 4; ++rf) {
            bf16x8 vb0 = *(const bf16x8*)(sV + (rf * 16 + q15) * 72 + quad * 8);
            bf16x8 vb1 = *(const bf16x8*)(sV + (rf * 16 + q15) * 72 + 32 + quad * 8);
            oacc[rf] = MFMA16(pa0, vb0, oacc[rf]);
            oacc[rf] = MFMA16(pa1, vb1, oacc[rf]);
        }
        lacc = MFMA16(pa0, vone, lacc);
        lacc = MFMA16(pa1, vone, lacc);
    }
#pragma unroll
    for (int rf = 0; rf < 4; ++rf)
#pragma unroll
        for (int e = 0; e < 4; ++e) {
            const float v = oacc[rf][e] / lacc[e];
            const size_t row = (size_t)(b * 1024 + qt * 64 + wave * 16 + quad * 4 + e);
            O[row * 1024 + h * 64 + rf * 16 + q15] = f2b(v);
        }
}

// ---------------------------------------------------------------------------
// LayerNorm over last dim (1024), eps=1e-3. One wave/row, 4 rows/block.
// ---------------------------------------------------------------------------
__global__ __launch_bounds__(256) void ln_k(
    const u16* __restrict__ y, const u16* __restrict__ g,
    const u16* __restrict__ be, void* __restrict__ out, const int* __restrict__ oflag)
{
    const int f = oflag ? *oflag : 0;
    const int tid = threadIdx.x, wave = tid >> 6, lane = tid & 63;
    const size_t row = (size_t)blockIdx.x * 4 + wave;
    const u16* p = y + row * 1024 + lane * 16;
    uint4 u0 = *(const uint4*)p;
    uint4 u1 = *(const uint4*)(p + 8);
    float v[16];
    unpack8(u0, v);
    unpack8(u1, v + 8);
    float s = 0.f, s2 = 0.f;
#pragma unroll
    for (int i = 0; i < 16; ++i) { s += v[i]; s2 += v[i] * v[i]; }
#pragma unroll
    for (int off = 1; off < 64; off <<= 1) {
        s += __shfl_xor(s, off, 64);
        s2 += __shfl_xor(s2, off, 64);
    }
    const float mean = s * (1.f / 1024.f);
    const float var = s2 * (1.f / 1024.f) - mean * mean;
    const float rstd = rsqrtf(var + 1e-3f);
    uint4 g0 = *(const uint4*)(g + lane * 16);
    uint4 g1 = *(const uint4*)(g + lane * 16 + 8);
    uint4 b0 = *(const uint4*)(be + lane * 16);
    uint4 b1 = *(const uint4*)(be + lane * 16 + 8);
    float gv[16], bv[16];
    unpack8(g0, gv); unpack8(g1, gv + 8);
    unpack8(b0, bv); unpack8(b1, bv + 8);
    float w[16];
#pragma unroll
    for (int i = 0; i < 16; ++i) w[i] = (v[i] - mean) * rstd * gv[i] + bv[i];
    if (f) {
        float* q = (float*)out + row * 1024 + lane * 16;
#pragma unroll
        for (int i = 0; i < 16; i += 4)
            *(float4*)(q + i) = make_float4(w[i], w[i + 1], w[i + 2], w[i + 3]);
    } else {
        uint4 o0, o1;
        o0.x = pack2(w[0], w[1]);   o0.y = pack2(w[2], w[3]);
        o0.z = pack2(w[4], w[5]);   o0.w = pack2(w[6], w[7]);
        o1.x = pack2(w[8], w[9]);   o1.y = pack2(w[10], w[11]);
        o1.z = pack2(w[12], w[13]); o1.w = pack2(w[14], w[15]);
        u16* q = (u16*)out + row * 1024 + lane * 16;
        *(uint4*)q = o0;
        *(uint4*)(q + 8) = o1;
    }
}

// ---------------------------------------------------------------------------
// Fused split-K reduce + residual + LayerNorm (FFN2 epilogue -> d_out).
// ---------------------------------------------------------------------------
__global__ __launch_bounds__(256) void ln3f_k(
    const float* __restrict__ p0, const float* __restrict__ p1,
    const u16* __restrict__ resid, const u16* __restrict__ g,
    const u16* __restrict__ be, void* __restrict__ out, const int* __restrict__ oflag)
{
    const int f = *oflag;
    const int tid = threadIdx.x, wave = tid >> 6, lane = tid & 63;
    const size_t row = (size_t)blockIdx.x * 4 + wave;
    const size_t base = row * 1024 + lane * 16;
    float v[16];
#pragma unroll
    for (int i = 0; i < 16; i += 4) {
        float4 a = *(const float4*)(p0 + base + i);
        float4 b = *(const float4*)(p1 + base + i);
        v[i + 0] = a.x + b.x; v[i + 1] = a.y + b.y;
        v[i + 2] = a.z + b.z; v[i + 3] = a.w + b.w;
    }
    uint4 r0 = *(const uint4*)(resid + base);
    uint4 r1 = *(const uint4*)(resid + base + 8);
    float rv[16];
    unpack8(r0, rv); unpack8(r1, rv + 8);
#pragma unroll
    for (int i = 0; i < 16; ++i) v[i] += rv[i];
    float s = 0.f, s2 = 0.f;
#pragma unroll
    for (int i = 0; i < 16; ++i) { s += v[i]; s2 += v[i] * v[i]; }
#pragma unroll
    for (int off = 1; off < 64; off <<= 1) {
        s += __shfl_xor(s, off, 64);
        s2 += __shfl_xor(s2, off, 64);
    }
    const float mean = s * (1.f / 1024.f);
    const float var = s2 * (1.f / 1024.f) - mean * mean;
    const float rstd = rsqrtf(var + 1e-3f);
    uint4 g0 = *(const uint4*)(g + lane * 16);
    uint4 g1 = *(const uint4*)(g + lane * 16 + 8);
    uint4 b0 = *(const uint4*)(be + lane * 16);
    uint4 b1 = *(const uint4*)(be + lane * 16 + 8);
    float gv[16], bv[16];
    unpack8(g0, gv); unpack8(g1, gv + 8);
    unpack8(b0, bv); unpack8(b1, bv + 8);
    float w[16];
#pragma unroll
    for (int i = 0; i < 16; ++i) w[i] = (v[i] - mean) * rstd * gv[i] + bv[i];
    if (f) {
        float* q = (float*)out + base;
#pragma unroll
        for (int i = 0; i < 16; i += 4)
            *(float4*)(q + i) = make_float4(w[i], w[i + 1], w[i + 2], w[i + 3]);
    } else {
        uint4 o0, o1;
        o0.x = pack2(w[0], w[1]);   o0.y = pack2(w[2], w[3]);
        o0.z = pack2(w[4], w[5]);   o0.w = pack2(w[6], w[7]);
        o1.x = pack2(w[8], w[9]);   o1.y = pack2(w[10], w[11]);
        o1.z = pack2(w[12], w[13]); o1.w = pack2(w[14], w[15]);
        u16* q = (u16*)out + base;
        *(uint4*)q = o0;
        *(uint4*)(q + 8) = o1;
    }
}

// ---------------------------------------------------------------------------
extern "C" void kernel_launch(void* const* d_in, const int* in_sizes, int n_in,
                              void* d_out, int out_size, void* d_ws, size_t ws_size,
                              hipStream_t stream)
{
    (void)in_sizes; (void)n_in; (void)out_size; (void)ws_size;
    const void* x   = d_in[0];
    const void* ctx = d_in[1];

    u16* ws = (u16*)d_ws;
    const size_t MEG = 1u << 20;
    u16* wT      = ws;               // 0..16M elems: transposed weights
    u16* bufx    = ws + 16 * MEG;
    u16* bufctx  = ws + 20 * MEG;
    u16* bufq    = ws + 24 * MEG;
    u16* bufk_sa = ws + 28 * MEG;
    u16* bufvt_sa= ws + 32 * MEG;
    u16* bufk_ca = ws + 36 * MEG;
    u16* bufvt_ca= ws + 40 * MEG;
    u16* bufo    = ws + 44 * MEG;
    u16* bufln   = ws + 48 * MEG;
    u16* small   = ws + 52 * MEG;
    int* flag    = (int*)(small + 20480);
    u16* bufh    = ws + 16 * MEG;    // FFN hidden (16..32M; bufx/ctx/q/k_sa dead)
    float* part  = (float*)(ws + 32 * MEG);  // 2x 4M f32 partials (32..48M)

    const int O_SABQ = 0,    O_SABK = 1024, O_SABV = 2048;
    const int O_CABK = 3072, O_CABV = 4096, O_CABQ = 5120;
    const int O_SABO = 6144, O_CABO = 7168;
    const int O_L1G = 8192,  O_L1B = 9216,  O_L2G = 10240, O_L2B = 11264;
    const int O_L3G = 12288, O_L3B = 13312, O_FB1 = 14336, O_FB2 = 18432;

    PtrTab tab;
    const void* sp[16] = { d_in[3], d_in[5], d_in[7], d_in[13], d_in[15], d_in[11],
                           d_in[9], d_in[17],
                           d_in[18], d_in[19], d_in[20], d_in[21], d_in[22], d_in[23],
                           d_in[25], d_in[27] };
    const int so[16] = { O_SABQ, O_SABK, O_SABV, O_CABK, O_CABV, O_CABQ, O_SABO, O_CABO,
                         O_L1G, O_L1B, O_L2G, O_L2B, O_L3G, O_L3B, O_FB1, O_FB2 };
    const int sc[16] = { 1024, 1024, 1024, 1024, 1024, 1024, 1024, 1024,
                         1024, 1024, 1024, 1024, 1024, 1024, 4096, 1024 };
    for (int i = 0; i < 16; ++i) { tab.p[i] = sp[i]; tab.off[i] = so[i]; tab.cnt[i] = sc[i]; }

    PtrTab tab6;
    const void* wp[6] = { d_in[2], d_in[4], d_in[6], d_in[12], d_in[14], d_in[10] };
    for (int i = 0; i < 6; ++i) tab6.p[i] = wp[i];

    const dim3 blk(256);
    const dim3 gN1(64, 8);

    // ---- dtype normalize + weight prep (R6-verified chain) ----
    detect_k<<<1, blk, 0, stream>>>((const u32*)x, flag);
    conv2_k<<<dim3(2048, 2), blk, 0, stream>>>(x, ctx, bufx, bufctx, 4 * MEG, flag);
    conv_small_k<<<dim3(16), blk, 0, stream>>>(tab, small, flag);
    transpose6_k<<<dim3(1, 16, 96), blk, 0, stream>>>(tab6, wT, flag);
    transpose_k<<<dim3(16, 16), blk, 0, stream>>>(d_in[8],  wT + 6 * MEG, 1024, 1024, flag);
    transpose_k<<<dim3(16, 16), blk, 0, stream>>>(d_in[16], wT + 7 * MEG, 1024, 1024, flag);
    transpose_k<<<dim3(64, 16), blk, 0, stream>>>(d_in[24], wT + 8 * MEG, 1024, 4096, flag);
    transpose_k<<<dim3(16, 64), blk, 0, stream>>>(d_in[26], wT + 12 * MEG, 4096, 1024, flag);

    // ---- fused projections (SA-Q pre-scaled by QSCALE) ----
    gemm_qkv_k<<<dim3(40, 32), blk, 0, stream>>>(bufx, bufctx, wT, small,
                                                 bufq, bufk_sa, bufvt_sa, bufk_ca, bufvt_ca);

    // ---- self-attention ----
    attn_k<<<dim3(1024), blk, 0, stream>>>(bufq, bufk_sa, bufvt_sa, bufo);
    gemm_n1k<<<gN1, blk, 0, stream>>>(bufo, wT + 6 * MEG, small + O_SABO, bufx,
                                      bufq, 4096, 1024, 1024, 0);
    ln_k<<<dim3(1024), blk, 0, stream>>>(bufq, small + O_L1G, small + O_L1B, bufln, nullptr);

    // ---- cross-attention (CA-Q pre-scaled via flags|4) ----
    gemm_n1k<<<gN1, blk, 0, stream>>>(bufln, wT + 5 * MEG, small + O_CABQ, nullptr,
                                      bufq, 4096, 1024, 1024, 4);
    attn_k<<<dim3(1024), blk, 0, stream>>>(bufq, bufk_ca, bufvt_ca, bufo);
    gemm_n1k<<<gN1, blk, 0, stream>>>(bufo, wT + 7 * MEG, small + O_CABO, bufln,
                                      bufq, 4096, 1024, 1024, 0);
    ln_k<<<dim3(1024), blk, 0, stream>>>(bufq, small + O_L2G, small + O_L2B, bufln, nullptr);

    // ---- FFN ----
    gemm_bt<<<dim3(32, 32), blk, 0, stream>>>(bufln, wT + 8 * MEG, small + O_FB1, nullptr,
                                              bufh, 4096, 4096, 1024, 1);
    gemm_skk<<<dim3(64, 8, 2), blk, 0, stream>>>(bufh, wT + 12 * MEG, small + O_FB2, part,
                                                 4096, 1024, 4096);
    ln3f_k<<<dim3(1024), blk, 0, stream>>>(part, part + (size_t)4 * MEG, bufln,
                                           small + O_L3G, small + O_L3B, d_out, flag);
}